// Round 4
// baseline (193.929 us; speedup 1.0000x reference)
//
#include <hip/hip_runtime.h>
#include <hip/hip_cooperative_groups.h>

namespace cg = cooperative_groups;

// Problem constants (match reference)
#define BB 32
#define SS 512
#define HH 1024
#define MM 8
#define NROWS (BB*SS)        // 16384 token rows
#define NSPANS (BB*SS*MM)    // 131072 spans
#define KSEL 4915            // int(0.3 * B * S)

// Workspace layout (bytes)
constexpr size_t OFF_QUERY = 0;                   // 1024 f32
constexpr size_t OFF_QD    = 4096;                // 16384 f32
constexpr size_t OFF_SD    = OFF_QD + 65536;      // 16384 f32
constexpr size_t OFF_KEYS  = OFF_SD + 65536;      // 131072 u32
constexpr size_t OFF_GOLD  = OFF_KEYS + 524288;   // 131072 u32
constexpr size_t OFF_H0    = OFF_GOLD + 524288;   // 256 u32
constexpr size_t OFF_H1    = OFF_H0 + 1024;       // 256 u32
constexpr size_t OFF_H2    = OFF_H1 + 1024;       // 256 u32
constexpr size_t OFF_H3    = OFF_H2 + 1024;       // 256 u32
constexpr size_t OFF_SCAL  = OFF_H3 + 1024;       // scalars (64 B)
constexpr size_t OFF_EQ    = OFF_SCAL + 64;       // 4096 u32 (not zeroed)
constexpr unsigned ZERO_WORDS = (unsigned)((OFF_EQ - OFF_H0) / 4);  // hists + scalars

struct Scal {
    float    loss_sum;
    unsigned n_valid;
    unsigned right_gt;
    unsigned eq_count;
    unsigned tau, T;     // debug / final
};

__device__ __forceinline__ unsigned sortable_key(float f) {
    unsigned b = __float_as_uint(f);
    return (b & 0x80000000u) ? ~b : (b | 0x80000000u);
}

// ---- K1: query = w_in @ term_weight + b_in; block 0 also zeros hist/scal ----
__global__ void k_query(const float* __restrict__ w_in, const float* __restrict__ tw,
                        const float* __restrict__ b_in, char* __restrict__ ws) {
    if (blockIdx.x == 0) {
        unsigned* z = (unsigned*)(ws + OFF_H0);
        for (unsigned i = threadIdx.x; i < ZERO_WORDS; i += 256) z[i] = 0u;
    }
    float* query = (float*)(ws + OFF_QUERY);
    int wave = (blockIdx.x * blockDim.x + threadIdx.x) >> 6;
    int lane = threadIdx.x & 63;
    if (wave >= HH) return;
    const float4* wrow = (const float4*)(w_in + (size_t)wave * HH);
    const float4* tv   = (const float4*)tw;
    float s = 0.f;
    #pragma unroll
    for (int p = 0; p < 4; ++p) {
        int c = p * 64 + lane;
        float4 w = wrow[c]; float4 t = tv[c];
        s += w.x*t.x + w.y*t.y + w.z*t.z + w.w*t.w;
    }
    #pragma unroll
    for (int o = 32; o > 0; o >>= 1) s += __shfl_down(s, o);
    if (lane == 0) query[wave] = s + b_in[wave];
}

// ---- K2: qd/sd = hidden · {query, score_w}, one wave per token row ----
__global__ void k_dots(const float* __restrict__ hs, const float* __restrict__ sw,
                       char* __restrict__ ws) {
    const float* query = (const float*)(ws + OFF_QUERY);
    float* qd = (float*)(ws + OFF_QD);
    float* sd = (float*)(ws + OFF_SD);
    int wave = (blockIdx.x * blockDim.x + threadIdx.x) >> 6;
    int lane = threadIdx.x & 63;
    if (wave >= NROWS) return;
    const float4* row = (const float4*)(hs + (size_t)wave * HH);
    const float4* qv  = (const float4*)query;
    const float4* sv  = (const float4*)sw;
    float a = 0.f, c2 = 0.f;
    #pragma unroll
    for (int p = 0; p < 4; ++p) {
        int c = p * 64 + lane;
        float4 h = row[c]; float4 q = qv[c]; float4 w = sv[c];
        a  += h.x*q.x + h.y*q.y + h.z*q.z + h.w*q.w;
        c2 += h.x*w.x + h.y*w.y + h.z*w.z + h.w*w.w;
    }
    #pragma unroll
    for (int o = 32; o > 0; o >>= 1) { a += __shfl_down(a, o); c2 += __shfl_down(c2, o); }
    if (lane == 0) { qd[wave] = a; sd[wave] = c2; }
}

// Block-parallel selection over a 256-bin hist: find bin c and remainder rem
// such that suffix_sum(c) >= Rin > suffix_sum(c+1); rem = Rin - suffix_sum(c+1).
__device__ __forceinline__ void block_sel(const unsigned* __restrict__ gh, unsigned Rin,
                                          unsigned* sbuf, unsigned* sres, int tid,
                                          unsigned& c, unsigned& rem) {
    __syncthreads();
    sbuf[tid] = gh[tid];
    __syncthreads();
    #pragma unroll
    for (int off = 1; off < 256; off <<= 1) {
        unsigned v = (tid + off < 256) ? sbuf[tid + off] : 0u;
        __syncthreads();
        sbuf[tid] += v;
        __syncthreads();
    }
    unsigned Scur  = sbuf[tid];
    unsigned Snext = (tid < 255) ? sbuf[tid + 1] : 0u;
    if (Scur >= Rin && Snext < Rin) { sres[0] = (unsigned)tid; sres[1] = Rin - Snext; }
    __syncthreads();
    c = sres[0]; rem = sres[1];
}

// ---- K3 (cooperative, 64 blocks x 256 = NROWS threads): everything else ----
// scores/keys/gold/loss + 4-level 8-bit radix select + precision + finalize.
// Fused to cut dispatch count: round-3 showed ~10us fixed overhead/dispatch
// dominating (work sum ~40us vs dur 151us over 10 dispatches).
__global__ __launch_bounds__(256)
void k_post(char* __restrict__ ws, const int* __restrict__ gold_mask,
            const int* __restrict__ seq_lengths, const float* __restrict__ score_b_p,
            float* __restrict__ out) {
    cg::grid_group grid = cg::this_grid();

    const float* qd = (const float*)(ws + OFF_QD);
    const float* sd = (const float*)(ws + OFF_SD);
    unsigned* keys  = (unsigned*)(ws + OFF_KEYS);
    unsigned* goldf = (unsigned*)(ws + OFF_GOLD);
    unsigned* h0    = (unsigned*)(ws + OFF_H0);
    unsigned* h1    = (unsigned*)(ws + OFF_H1);
    unsigned* h2    = (unsigned*)(ws + OFF_H2);
    unsigned* h3    = (unsigned*)(ws + OFF_H3);
    unsigned* eqL   = (unsigned*)(ws + OFF_EQ);
    Scal*     sc    = (Scal*)(ws + OFF_SCAL);

    __shared__ unsigned hloc[256];
    __shared__ unsigned sbuf[256];
    __shared__ unsigned sres[2];
    __shared__ float lsum[256];
    __shared__ int   lcnt[256];

    int tid = threadIdx.x;
    int t   = blockIdx.x * 256 + tid;          // [0, NROWS)

    // ---------- Phase A: scores, keys, gold, loss, top-8 hist ----------
    hloc[tid] = 0;
    __syncthreads();
    {
        int b = t >> 9, s = t & (SS - 1);
        int seqlen = seq_lengths[b];
        float sb = *score_b_p;

        uint4 gm0 = ((const uint4*)gold_mask)[t * 2];
        uint4 gm1 = ((const uint4*)gold_mask)[t * 2 + 1];
        unsigned gmv[8] = {gm0.x, gm0.y, gm0.z, gm0.w, gm1.x, gm1.y, gm1.z, gm1.w};

        unsigned kbuf[8], gbuf[8];
        float lloss = 0.f; int lval = 0;
        float maxv = 0.f, den = 0.f, num = 0.f;
        #pragma unroll
        for (int m = 0; m < MM; ++m) {
            int pos = s + m; if (pos > SS - 1) pos = SS - 1;
            float x = qd[b * SS + pos];
            float v = sd[b * SS + pos];
            if (m == 0)         { maxv = x; den = 1.f; num = v; }
            else if (x > maxv)  { float e = expf(maxv - x); den = den * e + 1.f; num = num * e + v; maxv = x; }
            else                { float e = expf(x - maxv); den += e; num += e * v; }
            float score = num / den + sb;
            bool valid = (s + m + 1) <= seqlen;
            bool gold  = valid && (gmv[m] == 0u);
            unsigned key = valid ? sortable_key(score) : 0u;
            kbuf[m] = key;
            gbuf[m] = gold ? 1u : 0u;
            if (valid) {
                atomicAdd(&hloc[key >> 24], 1u);
                lval++;
                float z = -score;
                float sp = (z > 0.f) ? (z + log1pf(expf(-z))) : log1pf(expf(z));
                lloss += gold ? sp : 0.69314718055994531f;
            }
        }
        ((uint4*)keys)[t * 2]      = make_uint4(kbuf[0], kbuf[1], kbuf[2], kbuf[3]);
        ((uint4*)keys)[t * 2 + 1]  = make_uint4(kbuf[4], kbuf[5], kbuf[6], kbuf[7]);
        ((uint4*)goldf)[t * 2]     = make_uint4(gbuf[0], gbuf[1], gbuf[2], gbuf[3]);
        ((uint4*)goldf)[t * 2 + 1] = make_uint4(gbuf[4], gbuf[5], gbuf[6], gbuf[7]);

        lsum[tid] = lloss; lcnt[tid] = lval;
    }
    __syncthreads();
    { unsigned hv = hloc[tid]; if (hv) atomicAdd(&h0[tid], hv); }
    for (int o = 128; o > 0; o >>= 1) {
        if (tid < o) { lsum[tid] += lsum[tid + o]; lcnt[tid] += lcnt[tid + o]; }
        __syncthreads();
    }
    if (tid == 0) {
        atomicAdd(&sc->loss_sum, lsum[0]);
        atomicAdd(&sc->n_valid, (unsigned)lcnt[0]);
    }
    grid.sync();

    // ---------- Phase B: radix levels 1..3 ----------
    unsigned c0, r0, c1, r1, c2, r2, c3, r3;

    // level 1: hist of byte2 among keys with byte3 == c0
    block_sel(h0, KSEL, sbuf, sres, tid, c0, r0);
    hloc[tid] = 0;
    __syncthreads();
    for (int i = t; i < NSPANS; i += NROWS) {
        unsigned k = keys[i];
        if (k != 0u && (k >> 24) == c0) atomicAdd(&hloc[(k >> 16) & 0xFFu], 1u);
    }
    __syncthreads();
    { unsigned v = hloc[tid]; if (v) atomicAdd(&h1[tid], v); }
    grid.sync();

    // level 2
    block_sel(h1, r0, sbuf, sres, tid, c1, r1);
    {
        unsigned pref = (c0 << 8) | c1;
        hloc[tid] = 0;
        __syncthreads();
        for (int i = t; i < NSPANS; i += NROWS) {
            unsigned k = keys[i];
            if (k != 0u && (k >> 16) == pref) atomicAdd(&hloc[(k >> 8) & 0xFFu], 1u);
        }
        __syncthreads();
        unsigned v = hloc[tid]; if (v) atomicAdd(&h2[tid], v);
    }
    grid.sync();

    // level 3
    block_sel(h2, r1, sbuf, sres, tid, c2, r2);
    {
        unsigned pref = (c0 << 16) | (c1 << 8) | c2;
        hloc[tid] = 0;
        __syncthreads();
        for (int i = t; i < NSPANS; i += NROWS) {
            unsigned k = keys[i];
            if (k != 0u && (k >> 8) == pref) atomicAdd(&hloc[k & 0xFFu], 1u);
        }
        __syncthreads();
        unsigned v = hloc[tid]; if (v) atomicAdd(&h3[tid], v);
    }
    grid.sync();

    // ---------- Phase C: tau/T, gold-above-tau, tie collection ----------
    block_sel(h3, r2, sbuf, sres, tid, c3, r3);
    unsigned tau = (c0 << 24) | (c1 << 16) | (c2 << 8) | c3;
    unsigned T   = r3;
    {
        int lgt = 0;
        for (int i = t; i < NSPANS; i += NROWS) {
            unsigned k = keys[i];
            if (k > tau) lgt += (int)goldf[i];
            else if (k == tau) {
                unsigned p = atomicAdd(&sc->eq_count, 1u);
                if (p < 4096) eqL[p] = (unsigned)i;
            }
        }
        #pragma unroll
        for (int o = 32; o > 0; o >>= 1) lgt += __shfl_down(lgt, o);
        if ((tid & 63) == 0 && lgt) atomicAdd(&sc->right_gt, (unsigned)lgt);
    }
    grid.sync();

    // ---------- Phase D: tie resolution (lowest-index-first) + outputs ----------
    if (blockIdx.x == 0 && tid == 0) {
        unsigned neq = sc->eq_count; if (neq > 4096) neq = 4096;
        unsigned extra = 0;
        if (T >= neq) {
            for (unsigned i = 0; i < neq; ++i) extra += goldf[eqL[i]];
        } else {
            unsigned prev = 0; bool first = true;
            for (unsigned it = 0; it < T; ++it) {
                unsigned mn = 0xFFFFFFFFu;
                for (unsigned i = 0; i < neq; ++i) {
                    unsigned v = eqL[i];
                    if ((first || v > prev) && v < mn) mn = v;
                }
                if (mn == 0xFFFFFFFFu) break;
                extra += goldf[mn];
                prev = mn; first = false;
            }
        }
        float loss = sc->loss_sum / (float)sc->n_valid;
        float prec = (float)(sc->right_gt + extra) / (float)KSEL;
        out[0] = loss;
        out[1] = prec;
    }
}

extern "C" void kernel_launch(void* const* d_in, const int* in_sizes, int n_in,
                              void* d_out, int out_size, void* d_ws, size_t ws_size,
                              hipStream_t stream) {
    const float* hidden   = (const float*)d_in[0];
    const float* term_w   = (const float*)d_in[1];
    const float* w_in     = (const float*)d_in[2];
    const float* b_in     = (const float*)d_in[3];
    const float* score_w  = (const float*)d_in[4];
    const float* score_b  = (const float*)d_in[5];
    const int*   seq_len  = (const int*)d_in[6];
    const int*   gmask    = (const int*)d_in[7];
    float* out            = (float*)d_out;
    char*  ws             = (char*)d_ws;

    k_query<<<256, 256, 0, stream>>>(w_in, term_w, b_in, ws);
    k_dots <<<4096, 256, 0, stream>>>(hidden, score_w, ws);

    void* args[] = { (void*)&ws, (void*)&gmask, (void*)&seq_len,
                     (void*)&score_b, (void*)&out };
    hipLaunchCooperativeKernel((void*)k_post, dim3(64), dim3(256), args, 0, stream);
}

// Round 5
// 142.730 us; speedup vs baseline: 1.3587x; 1.3587x over previous
//
#include <hip/hip_runtime.h>

// Problem constants (match reference)
#define BB 32
#define SS 512
#define HH 1024
#define MM 8
#define NROWS (BB*SS)        // 16384 token rows
#define NSPANS (BB*SS*MM)    // 131072 spans
#define KSEL 4915            // int(0.3 * B * S)

// Workspace layout (bytes)
constexpr size_t OFF_QUERY = 0;                    // 1024 f32
constexpr size_t OFF_QD    = 4096;                 // 16384 f32
constexpr size_t OFF_SD    = OFF_QD + 65536;       // 16384 f32
constexpr size_t OFF_KEYS  = OFF_SD + 65536;       // 131072 u32
constexpr size_t OFF_GOLD  = OFF_KEYS + 524288;    // 131072 u32
constexpr size_t OFF_H0    = OFF_GOLD + 524288;    // 4096 u32 (top-12 bits)
constexpr size_t OFF_H1    = OFF_H0 + 16384;       // 4096 u32 (bits 8..20)
constexpr size_t OFF_H2    = OFF_H1 + 16384;       // 256 u32  (bits 0..8)
constexpr size_t OFF_SCAL  = OFF_H2 + 1024;        // scalars (64 B)
constexpr size_t OFF_EQ    = OFF_SCAL + 64;        // 4096 u32 (not zeroed)
constexpr unsigned ZERO_WORDS = (unsigned)((OFF_EQ - OFF_H0) / 4);

struct Scal {
    float    loss_sum;
    unsigned n_valid;
    unsigned right_gt;
    unsigned eq_count;
    unsigned done;       // last-block-done counter
};

__device__ __forceinline__ unsigned sortable_key(float f) {
    unsigned b = __float_as_uint(f);
    return (b & 0x80000000u) ? ~b : (b | 0x80000000u);
}

// ---- selection over a 4096-bin global hist (256 threads, 16 bins/thread) ----
// Finds c = max{c : suffix_sum(c) >= R}, rem = R - suffix_sum(c+1).
__device__ __forceinline__ void sel4096(const unsigned* __restrict__ gh, unsigned R,
                                        unsigned* sp, unsigned* sres, int tid,
                                        unsigned& c, unsigned& rem) {
    unsigned loc[16]; unsigned lsumv = 0;
    #pragma unroll
    for (int i = 0; i < 16; ++i) { loc[i] = gh[tid * 16 + i]; lsumv += loc[i]; }
    __syncthreads();
    sp[tid] = lsumv;
    __syncthreads();
    #pragma unroll
    for (int off = 1; off < 256; off <<= 1) {
        unsigned v = (tid + off < 256) ? sp[tid + off] : 0u;
        __syncthreads();
        sp[tid] += v;
        __syncthreads();
    }
    unsigned Pt  = sp[tid];
    unsigned Pt1 = (tid < 255) ? sp[tid + 1] : 0u;
    if (Pt >= R && Pt1 < R) {
        unsigned cum = Pt1;
        #pragma unroll
        for (int i = 15; i >= 0; --i) {
            unsigned h = loc[i];
            if (cum + h >= R) { sres[0] = (unsigned)(tid * 16 + i); sres[1] = R - cum; break; }
            cum += h;
        }
    }
    __syncthreads();
    c = sres[0]; rem = sres[1];
    __syncthreads();
}

// ---- selection over a 256-bin global hist ----
__device__ __forceinline__ void sel256(const unsigned* __restrict__ gh, unsigned R,
                                       unsigned* sp, unsigned* sres, int tid,
                                       unsigned& c, unsigned& rem) {
    __syncthreads();
    sp[tid] = gh[tid];
    __syncthreads();
    #pragma unroll
    for (int off = 1; off < 256; off <<= 1) {
        unsigned v = (tid + off < 256) ? sp[tid + off] : 0u;
        __syncthreads();
        sp[tid] += v;
        __syncthreads();
    }
    unsigned Pt  = sp[tid];
    unsigned Pt1 = (tid < 255) ? sp[tid + 1] : 0u;
    if (Pt >= R && Pt1 < R) { sres[0] = (unsigned)tid; sres[1] = R - Pt1; }
    __syncthreads();
    c = sres[0]; rem = sres[1];
    __syncthreads();
}

// ---- K1: query = w_in @ term_weight + b_in; block 0 also zeros hists/scal ----
__global__ void k_query(const float* __restrict__ w_in, const float* __restrict__ tw,
                        const float* __restrict__ b_in, char* __restrict__ ws) {
    if (blockIdx.x == 0) {
        unsigned* z = (unsigned*)(ws + OFF_H0);
        for (unsigned i = threadIdx.x; i < ZERO_WORDS; i += 256) z[i] = 0u;
    }
    float* query = (float*)(ws + OFF_QUERY);
    int wave = (blockIdx.x * blockDim.x + threadIdx.x) >> 6;
    int lane = threadIdx.x & 63;
    if (wave >= HH) return;
    const float4* wrow = (const float4*)(w_in + (size_t)wave * HH);
    const float4* tv   = (const float4*)tw;
    float s = 0.f;
    #pragma unroll
    for (int p = 0; p < 4; ++p) {
        int c = p * 64 + lane;
        float4 w = wrow[c]; float4 t = tv[c];
        s += w.x*t.x + w.y*t.y + w.z*t.z + w.w*t.w;
    }
    #pragma unroll
    for (int o = 32; o > 0; o >>= 1) s += __shfl_down(s, o);
    if (lane == 0) query[wave] = s + b_in[wave];
}

// ---- K2: qd/sd = hidden · {query, score_w}, one wave per token row ----
// Only real HBM consumer (64 MB read) — HBM-roofline bound (~10 us).
__global__ void k_dots(const float* __restrict__ hs, const float* __restrict__ sw,
                       char* __restrict__ ws) {
    const float* query = (const float*)(ws + OFF_QUERY);
    float* qd = (float*)(ws + OFF_QD);
    float* sd = (float*)(ws + OFF_SD);
    int wave = (blockIdx.x * blockDim.x + threadIdx.x) >> 6;
    int lane = threadIdx.x & 63;
    if (wave >= NROWS) return;
    const float4* row = (const float4*)(hs + (size_t)wave * HH);
    const float4* qv  = (const float4*)query;
    const float4* sv  = (const float4*)sw;
    float a = 0.f, c2 = 0.f;
    #pragma unroll
    for (int p = 0; p < 4; ++p) {
        int c = p * 64 + lane;
        float4 h = row[c]; float4 q = qv[c]; float4 w = sv[c];
        a  += h.x*q.x + h.y*q.y + h.z*q.z + h.w*q.w;
        c2 += h.x*w.x + h.y*w.y + h.z*w.z + h.w*w.w;
    }
    #pragma unroll
    for (int o = 32; o > 0; o >>= 1) { a += __shfl_down(a, o); c2 += __shfl_down(c2, o); }
    if (lane == 0) { qd[wave] = a; sd[wave] = c2; }
}

// ---- K3: scores/keys/gold/loss + 12-bit LDS hist (h0) ----
__global__ void k_scores(const int* __restrict__ gold_mask, const int* __restrict__ seq_lengths,
                         const float* __restrict__ score_b_p, char* __restrict__ ws) {
    const float* qd = (const float*)(ws + OFF_QD);
    const float* sd = (const float*)(ws + OFF_SD);
    unsigned* keys  = (unsigned*)(ws + OFF_KEYS);
    unsigned* goldf = (unsigned*)(ws + OFF_GOLD);
    unsigned* h0    = (unsigned*)(ws + OFF_H0);
    Scal*     sc    = (Scal*)(ws + OFF_SCAL);

    __shared__ unsigned hloc[4096];
    __shared__ float lsum[256];
    __shared__ int   lcnt[256];
    for (int i = threadIdx.x; i < 4096; i += 256) hloc[i] = 0;
    __syncthreads();

    int t = blockIdx.x * 256 + threadIdx.x;   // [0, NROWS)
    int b = t >> 9, s = t & (SS - 1);
    int seqlen = seq_lengths[b];
    float sb = *score_b_p;

    uint4 gm0 = ((const uint4*)gold_mask)[t * 2];
    uint4 gm1 = ((const uint4*)gold_mask)[t * 2 + 1];
    unsigned gmv[8] = {gm0.x, gm0.y, gm0.z, gm0.w, gm1.x, gm1.y, gm1.z, gm1.w};

    unsigned kbuf[8], gbuf[8];
    float lloss = 0.f; int lval = 0;
    float maxv = 0.f, den = 0.f, num = 0.f;
    #pragma unroll
    for (int m = 0; m < MM; ++m) {
        int pos = s + m; if (pos > SS - 1) pos = SS - 1;
        float x = qd[b * SS + pos];
        float v = sd[b * SS + pos];
        if (m == 0)         { maxv = x; den = 1.f; num = v; }
        else if (x > maxv)  { float e = expf(maxv - x); den = den * e + 1.f; num = num * e + v; maxv = x; }
        else                { float e = expf(x - maxv); den += e; num += e * v; }
        float score = num / den + sb;
        bool valid = (s + m + 1) <= seqlen;
        bool gold  = valid && (gmv[m] == 0u);
        unsigned key = valid ? sortable_key(score) : 0u;
        kbuf[m] = key;
        gbuf[m] = gold ? 1u : 0u;
        if (valid) {
            atomicAdd(&hloc[key >> 20], 1u);
            lval++;
            float z = -score;
            float sp = (z > 0.f) ? (z + log1pf(expf(-z))) : log1pf(expf(z));
            lloss += gold ? sp : 0.69314718055994531f;
        }
    }
    ((uint4*)keys)[t * 2]      = make_uint4(kbuf[0], kbuf[1], kbuf[2], kbuf[3]);
    ((uint4*)keys)[t * 2 + 1]  = make_uint4(kbuf[4], kbuf[5], kbuf[6], kbuf[7]);
    ((uint4*)goldf)[t * 2]     = make_uint4(gbuf[0], gbuf[1], gbuf[2], gbuf[3]);
    ((uint4*)goldf)[t * 2 + 1] = make_uint4(gbuf[4], gbuf[5], gbuf[6], gbuf[7]);

    lsum[threadIdx.x] = lloss; lcnt[threadIdx.x] = lval;
    __syncthreads();
    for (int i = threadIdx.x; i < 4096; i += 256) {
        unsigned v = hloc[i]; if (v) atomicAdd(&h0[i], v);
    }
    for (int o = 128; o > 0; o >>= 1) {
        if (threadIdx.x < o) { lsum[threadIdx.x] += lsum[threadIdx.x + o]; lcnt[threadIdx.x] += lcnt[threadIdx.x + o]; }
        __syncthreads();
    }
    if (threadIdx.x == 0) {
        atomicAdd(&sc->loss_sum, lsum[0]);
        atomicAdd(&sc->n_valid, (unsigned)lcnt[0]);
    }
}

// ---- K4: level-1 — select c0 from h0 (redundant/block), hist bits [8,20) ----
__global__ void k_lvl1(char* __restrict__ ws) {
    const unsigned* keys = (const unsigned*)(ws + OFF_KEYS);
    const unsigned* h0   = (const unsigned*)(ws + OFF_H0);
    unsigned* h1         = (unsigned*)(ws + OFF_H1);
    __shared__ unsigned hloc[4096];
    __shared__ unsigned sp[256];
    __shared__ unsigned sres[2];
    int tid = threadIdx.x;
    unsigned c0, r0;
    sel4096(h0, KSEL, sp, sres, tid, c0, r0);
    for (int i = tid; i < 4096; i += 256) hloc[i] = 0;
    __syncthreads();
    for (int i = blockIdx.x * 256 + tid; i < NSPANS; i += gridDim.x * 256) {
        unsigned k = keys[i];
        if (k != 0u && (k >> 20) == c0) atomicAdd(&hloc[(k >> 8) & 0xFFFu], 1u);
    }
    __syncthreads();
    for (int i = tid; i < 4096; i += 256) {
        unsigned v = hloc[i]; if (v) atomicAdd(&h1[i], v);
    }
}

// ---- K5: level-2 — select c1 from h1, hist bits [0,8) ----
__global__ void k_lvl2(char* __restrict__ ws) {
    const unsigned* keys = (const unsigned*)(ws + OFF_KEYS);
    const unsigned* h0   = (const unsigned*)(ws + OFF_H0);
    const unsigned* h1   = (const unsigned*)(ws + OFF_H1);
    unsigned* h2         = (unsigned*)(ws + OFF_H2);
    __shared__ unsigned hloc[256];
    __shared__ unsigned sp[256];
    __shared__ unsigned sres[2];
    int tid = threadIdx.x;
    unsigned c0, r0, c1, r1;
    sel4096(h0, KSEL, sp, sres, tid, c0, r0);
    sel4096(h1, r0,   sp, sres, tid, c1, r1);
    unsigned pref = (c0 << 12) | c1;   // top-24 bits of tau
    hloc[tid] = 0;
    __syncthreads();
    for (int i = blockIdx.x * 256 + tid; i < NSPANS; i += gridDim.x * 256) {
        unsigned k = keys[i];
        if (k != 0u && (k >> 8) == pref) atomicAdd(&hloc[k & 0xFFu], 1u);
    }
    __syncthreads();
    { unsigned v = hloc[tid]; if (v) atomicAdd(&h2[tid], v); }
}

// ---- K6: final — tau/T, gold-above, tie collect, last block finalizes ----
__global__ void k_count_final(char* __restrict__ ws, float* __restrict__ out) {
    const unsigned* keys  = (const unsigned*)(ws + OFF_KEYS);
    const unsigned* goldf = (const unsigned*)(ws + OFF_GOLD);
    const unsigned* h0    = (const unsigned*)(ws + OFF_H0);
    const unsigned* h1    = (const unsigned*)(ws + OFF_H1);
    const unsigned* h2    = (const unsigned*)(ws + OFF_H2);
    unsigned* eqL         = (unsigned*)(ws + OFF_EQ);
    Scal*     sc          = (Scal*)(ws + OFF_SCAL);
    __shared__ unsigned sp[256];
    __shared__ unsigned sres[2];
    __shared__ unsigned is_last;
    int tid = threadIdx.x;
    unsigned c0, r0, c1, r1, c2, r2;
    sel4096(h0, KSEL, sp, sres, tid, c0, r0);
    sel4096(h1, r0,   sp, sres, tid, c1, r1);
    sel256 (h2, r1,   sp, sres, tid, c2, r2);
    unsigned tau = (c0 << 20) | (c1 << 8) | c2;
    unsigned T   = r2;

    int lgt = 0;
    for (int i = blockIdx.x * 256 + tid; i < NSPANS; i += gridDim.x * 256) {
        unsigned k = keys[i];
        if (k > tau) lgt += (int)goldf[i];
        else if (k == tau) {
            unsigned p = atomicAdd(&sc->eq_count, 1u);
            if (p < 4096) atomicExch(&eqL[p], (unsigned)i);
        }
    }
    #pragma unroll
    for (int o = 32; o > 0; o >>= 1) lgt += __shfl_down(lgt, o);
    if ((tid & 63) == 0 && lgt) atomicAdd(&sc->right_gt, (unsigned)lgt);

    __threadfence();
    __syncthreads();
    if (tid == 0) {
        unsigned prev = atomicAdd(&sc->done, 1u);
        is_last = (prev == gridDim.x - 1) ? 1u : 0u;
    }
    __syncthreads();
    if (is_last && tid == 0) {
        __threadfence();
        unsigned neq = __hip_atomic_load(&sc->eq_count, __ATOMIC_RELAXED, __HIP_MEMORY_SCOPE_AGENT);
        if (neq > 4096) neq = 4096;
        unsigned extra = 0;
        if (T >= neq) {
            for (unsigned i = 0; i < neq; ++i) {
                unsigned v = __hip_atomic_load(&eqL[i], __ATOMIC_RELAXED, __HIP_MEMORY_SCOPE_AGENT);
                extra += goldf[v];
            }
        } else {
            unsigned prev2 = 0; bool first = true;
            for (unsigned it = 0; it < T; ++it) {
                unsigned mn = 0xFFFFFFFFu;
                for (unsigned i = 0; i < neq; ++i) {
                    unsigned v = __hip_atomic_load(&eqL[i], __ATOMIC_RELAXED, __HIP_MEMORY_SCOPE_AGENT);
                    if ((first || v > prev2) && v < mn) mn = v;
                }
                if (mn == 0xFFFFFFFFu) break;
                extra += goldf[mn];
                prev2 = mn; first = false;
            }
        }
        float ls = __hip_atomic_load(&sc->loss_sum, __ATOMIC_RELAXED, __HIP_MEMORY_SCOPE_AGENT);
        unsigned nv = __hip_atomic_load(&sc->n_valid, __ATOMIC_RELAXED, __HIP_MEMORY_SCOPE_AGENT);
        unsigned rg = __hip_atomic_load(&sc->right_gt, __ATOMIC_RELAXED, __HIP_MEMORY_SCOPE_AGENT);
        out[0] = ls / (float)nv;
        out[1] = (float)(rg + extra) / (float)KSEL;
    }
}

extern "C" void kernel_launch(void* const* d_in, const int* in_sizes, int n_in,
                              void* d_out, int out_size, void* d_ws, size_t ws_size,
                              hipStream_t stream) {
    const float* hidden   = (const float*)d_in[0];
    const float* term_w   = (const float*)d_in[1];
    const float* w_in     = (const float*)d_in[2];
    const float* b_in     = (const float*)d_in[3];
    const float* score_w  = (const float*)d_in[4];
    const float* score_b  = (const float*)d_in[5];
    const int*   seq_len  = (const int*)d_in[6];
    const int*   gmask    = (const int*)d_in[7];
    float* out            = (float*)d_out;
    char*  ws             = (char*)d_ws;

    k_query      <<<256, 256, 0, stream>>>(w_in, term_w, b_in, ws);
    k_dots       <<<4096, 256, 0, stream>>>(hidden, score_w, ws);
    k_scores     <<<64, 256, 0, stream>>>(gmask, seq_len, score_b, ws);
    k_lvl1       <<<64, 256, 0, stream>>>(ws);
    k_lvl2       <<<64, 256, 0, stream>>>(ws);
    k_count_final<<<64, 256, 0, stream>>>(ws, out);
}

// Round 6
// 136.425 us; speedup vs baseline: 1.4215x; 1.0462x over previous
//
#include <hip/hip_runtime.h>

// Problem constants (match reference)
#define BB 32
#define SS 512
#define HH 1024
#define MM 8
#define NROWS (BB*SS)        // 16384 token rows
#define NSPANS (BB*SS*MM)    // 131072 spans
#define KSEL 4915            // int(0.3 * B * S)

// Workspace layout (bytes)
constexpr size_t OFF_QUERY = 0;                    // 1024 f32
constexpr size_t OFF_QD    = 4096;                 // 16384 f32
constexpr size_t OFF_SD    = OFF_QD + 65536;       // 16384 f32
constexpr size_t OFF_KEYS  = OFF_SD + 65536;       // 131072 u32
constexpr size_t OFF_H0    = OFF_KEYS + 524288;    // 4096 u32 count hist (top-12 bits)
constexpr size_t OFF_GH    = OFF_H0 + 16384;       // 4096 u32 gold hist
constexpr size_t OFF_SCAL  = OFF_GH + 16384;       // scalars (64 B)
constexpr size_t OFF_CKEY  = OFF_SCAL + 64;        // 131072 u32 compact low-20 keys
constexpr size_t OFF_CIDX  = OFF_CKEY + 524288;    // 131072 u32 (idx<<1)|gold
constexpr unsigned ZERO_WORDS = (unsigned)((OFF_SCAL + 64 - OFF_H0) / 4);

struct Scal {
    float    loss_sum;
    unsigned n_valid;
    unsigned nB;         // compact-list size
};

__device__ __forceinline__ unsigned sortable_key(float f) {
    unsigned b = __float_as_uint(f);
    return (b & 0x80000000u) ? ~b : (b | 0x80000000u);
}

// ---- selection over a 4096-bin hist (256 threads, 16 bins/thread) ----
// Finds c = max{c : suffix_sum(c) >= R}, rem = R - suffix_sum(c+1).
// Works on global or LDS hist pointer.
__device__ __forceinline__ void sel4096(const unsigned* __restrict__ gh, unsigned R,
                                        unsigned* sp, unsigned* sres, int tid,
                                        unsigned& c, unsigned& rem) {
    unsigned loc[16]; unsigned lsumv = 0;
    #pragma unroll
    for (int i = 0; i < 16; ++i) { loc[i] = gh[tid * 16 + i]; lsumv += loc[i]; }
    __syncthreads();
    sp[tid] = lsumv;
    __syncthreads();
    #pragma unroll
    for (int off = 1; off < 256; off <<= 1) {
        unsigned v = (tid + off < 256) ? sp[tid + off] : 0u;
        __syncthreads();
        sp[tid] += v;
        __syncthreads();
    }
    unsigned Pt  = sp[tid];
    unsigned Pt1 = (tid < 255) ? sp[tid + 1] : 0u;
    if (Pt >= R && Pt1 < R) {
        unsigned cum = Pt1;
        #pragma unroll
        for (int i = 15; i >= 0; --i) {
            unsigned h = loc[i];
            if (cum + h >= R) { sres[0] = (unsigned)(tid * 16 + i); sres[1] = R - cum; break; }
            cum += h;
        }
    }
    __syncthreads();
    c = sres[0]; rem = sres[1];
    __syncthreads();
}

// ---- selection over a 256-bin LDS hist ----
__device__ __forceinline__ void sel256(const unsigned* __restrict__ gh, unsigned R,
                                       unsigned* sp, unsigned* sres, int tid,
                                       unsigned& c, unsigned& rem) {
    __syncthreads();
    sp[tid] = gh[tid];
    __syncthreads();
    #pragma unroll
    for (int off = 1; off < 256; off <<= 1) {
        unsigned v = (tid + off < 256) ? sp[tid + off] : 0u;
        __syncthreads();
        sp[tid] += v;
        __syncthreads();
    }
    unsigned Pt  = sp[tid];
    unsigned Pt1 = (tid < 255) ? sp[tid + 1] : 0u;
    if (Pt >= R && Pt1 < R) { sres[0] = (unsigned)tid; sres[1] = R - Pt1; }
    __syncthreads();
    c = sres[0]; rem = sres[1];
    __syncthreads();
}

// ---- K1: query = w_in @ term_weight + b_in; block 0 also zeros hists/scal ----
__global__ void k_query(const float* __restrict__ w_in, const float* __restrict__ tw,
                        const float* __restrict__ b_in, char* __restrict__ ws) {
    if (blockIdx.x == 0) {
        unsigned* z = (unsigned*)(ws + OFF_H0);
        for (unsigned i = threadIdx.x; i < ZERO_WORDS; i += 256) z[i] = 0u;
    }
    float* query = (float*)(ws + OFF_QUERY);
    int wave = (blockIdx.x * blockDim.x + threadIdx.x) >> 6;
    int lane = threadIdx.x & 63;
    if (wave >= HH) return;
    const float4* wrow = (const float4*)(w_in + (size_t)wave * HH);
    const float4* tv   = (const float4*)tw;
    float s = 0.f;
    #pragma unroll
    for (int p = 0; p < 4; ++p) {
        int c = p * 64 + lane;
        float4 w = wrow[c]; float4 t = tv[c];
        s += w.x*t.x + w.y*t.y + w.z*t.z + w.w*t.w;
    }
    #pragma unroll
    for (int o = 32; o > 0; o >>= 1) s += __shfl_down(s, o);
    if (lane == 0) query[wave] = s + b_in[wave];
}

// ---- K2: qd/sd = hidden · {query, score_w}, one wave per token row ----
// Only real HBM consumer (64 MB read) — HBM-roofline bound (~11 us).
__global__ void k_dots(const float* __restrict__ hs, const float* __restrict__ sw,
                       char* __restrict__ ws) {
    const float* query = (const float*)(ws + OFF_QUERY);
    float* qd = (float*)(ws + OFF_QD);
    float* sd = (float*)(ws + OFF_SD);
    int wave = (blockIdx.x * blockDim.x + threadIdx.x) >> 6;
    int lane = threadIdx.x & 63;
    if (wave >= NROWS) return;
    const float4* row = (const float4*)(hs + (size_t)wave * HH);
    const float4* qv  = (const float4*)query;
    const float4* sv  = (const float4*)sw;
    float a = 0.f, c2 = 0.f;
    #pragma unroll
    for (int p = 0; p < 4; ++p) {
        int c = p * 64 + lane;
        float4 h = row[c]; float4 q = qv[c]; float4 w = sv[c];
        a  += h.x*q.x + h.y*q.y + h.z*q.z + h.w*q.w;
        c2 += h.x*w.x + h.y*w.y + h.z*w.z + h.w*w.w;
    }
    #pragma unroll
    for (int o = 32; o > 0; o >>= 1) { a += __shfl_down(a, o); c2 += __shfl_down(c2, o); }
    if (lane == 0) { qd[wave] = a; sd[wave] = c2; }
}

// ---- K3: scores/keys/loss + 12-bit count hist + 12-bit gold hist ----
__global__ void k_scores(const int* __restrict__ gold_mask, const int* __restrict__ seq_lengths,
                         const float* __restrict__ score_b_p, char* __restrict__ ws) {
    const float* qd = (const float*)(ws + OFF_QD);
    const float* sd = (const float*)(ws + OFF_SD);
    unsigned* keys  = (unsigned*)(ws + OFF_KEYS);
    unsigned* h0    = (unsigned*)(ws + OFF_H0);
    unsigned* gh0   = (unsigned*)(ws + OFF_GH);
    Scal*     sc    = (Scal*)(ws + OFF_SCAL);

    __shared__ unsigned hloc[4096];
    __shared__ unsigned gloc[4096];
    __shared__ float lsum[256];
    __shared__ int   lcnt[256];
    for (int i = threadIdx.x; i < 4096; i += 256) { hloc[i] = 0; gloc[i] = 0; }
    __syncthreads();

    int t = blockIdx.x * 256 + threadIdx.x;   // [0, NROWS)
    int b = t >> 9, s = t & (SS - 1);
    int seqlen = seq_lengths[b];
    float sb = *score_b_p;

    uint4 gm0 = ((const uint4*)gold_mask)[t * 2];
    uint4 gm1 = ((const uint4*)gold_mask)[t * 2 + 1];
    unsigned gmv[8] = {gm0.x, gm0.y, gm0.z, gm0.w, gm1.x, gm1.y, gm1.z, gm1.w};

    unsigned kbuf[8];
    float lloss = 0.f; int lval = 0;
    float maxv = 0.f, den = 0.f, num = 0.f;
    #pragma unroll
    for (int m = 0; m < MM; ++m) {
        int pos = s + m; if (pos > SS - 1) pos = SS - 1;
        float x = qd[b * SS + pos];
        float v = sd[b * SS + pos];
        if (m == 0)         { maxv = x; den = 1.f; num = v; }
        else if (x > maxv)  { float e = expf(maxv - x); den = den * e + 1.f; num = num * e + v; maxv = x; }
        else                { float e = expf(x - maxv); den += e; num += e * v; }
        float score = num / den + sb;
        bool valid = (s + m + 1) <= seqlen;
        bool gold  = valid && (gmv[m] == 0u);
        unsigned key = valid ? sortable_key(score) : 0u;
        kbuf[m] = key;
        if (valid) {
            atomicAdd(&hloc[key >> 20], 1u);
            if (gold) atomicAdd(&gloc[key >> 20], 1u);
            lval++;
            float z = -score;
            float sp = (z > 0.f) ? (z + log1pf(expf(-z))) : log1pf(expf(z));
            lloss += gold ? sp : 0.69314718055994531f;
        }
    }
    ((uint4*)keys)[t * 2]      = make_uint4(kbuf[0], kbuf[1], kbuf[2], kbuf[3]);
    ((uint4*)keys)[t * 2 + 1]  = make_uint4(kbuf[4], kbuf[5], kbuf[6], kbuf[7]);

    lsum[threadIdx.x] = lloss; lcnt[threadIdx.x] = lval;
    __syncthreads();
    for (int i = threadIdx.x; i < 4096; i += 256) {
        unsigned v = hloc[i]; if (v) atomicAdd(&h0[i], v);
        unsigned g = gloc[i]; if (g) atomicAdd(&gh0[i], g);
    }
    for (int o = 128; o > 0; o >>= 1) {
        if (threadIdx.x < o) { lsum[threadIdx.x] += lsum[threadIdx.x + o]; lcnt[threadIdx.x] += lcnt[threadIdx.x + o]; }
        __syncthreads();
    }
    if (threadIdx.x == 0) {
        atomicAdd(&sc->loss_sum, lsum[0]);
        atomicAdd(&sc->n_valid, (unsigned)lcnt[0]);
    }
}

// ---- K4: compact boundary-bucket entries (top12 == c0) into small list ----
__global__ void k_compact(char* __restrict__ ws, const int* __restrict__ gold_mask) {
    const unsigned* keys = (const unsigned*)(ws + OFF_KEYS);
    const unsigned* h0   = (const unsigned*)(ws + OFF_H0);
    unsigned* ckey       = (unsigned*)(ws + OFF_CKEY);
    unsigned* cidx       = (unsigned*)(ws + OFF_CIDX);
    Scal*     sc         = (Scal*)(ws + OFF_SCAL);
    __shared__ unsigned sp[256];
    __shared__ unsigned sres[2];
    int tid = threadIdx.x;
    unsigned c0, r0;
    sel4096(h0, KSEL, sp, sres, tid, c0, r0);
    int lane = tid & 63;
    // uniform trip count: NSPANS / (64*256) = 8 iterations for every thread
    for (int i = blockIdx.x * 256 + tid; i < NSPANS; i += 64 * 256) {
        unsigned k = keys[i];
        bool match = (k >> 20) == c0;   // c0 >= 2048 so k==0 (invalid) never matches
        unsigned long long m = __ballot(match);
        if (m) {
            int leader = __ffsll(m) - 1;
            unsigned base = 0;
            if (lane == leader) base = atomicAdd(&sc->nB, (unsigned)__popcll(m));
            base = __shfl(base, leader);
            if (match) {
                unsigned pos = base + (unsigned)__popcll(m & ((1ull << lane) - 1ull));
                ckey[pos] = k & 0xFFFFFu;
                unsigned gold = (gold_mask[i] == 0) ? 1u : 0u;
                cidx[pos] = ((unsigned)i << 1) | gold;
            }
        }
    }
}

// ---- K5 (1 block): resolve low-20 bits on compact list, finalize outputs ----
__global__ void k_final(char* __restrict__ ws, float* __restrict__ out) {
    const unsigned* h0   = (const unsigned*)(ws + OFF_H0);
    const unsigned* gh0  = (const unsigned*)(ws + OFF_GH);
    const unsigned* ckey = (const unsigned*)(ws + OFF_CKEY);
    const unsigned* cidx = (const unsigned*)(ws + OFF_CIDX);
    Scal*     sc         = (Scal*)(ws + OFF_SCAL);

    __shared__ unsigned hloc[4096];
    __shared__ unsigned tie[4096];
    __shared__ unsigned sp[256];
    __shared__ unsigned sres[2];
    __shared__ unsigned red[256];
    __shared__ unsigned tcnt;
    int tid = threadIdx.x;

    unsigned c0, r0;
    sel4096(h0, KSEL, sp, sres, tid, c0, r0);

    // gold count in buckets strictly above c0 (all unconditionally in top-K)
    unsigned g = 0;
    #pragma unroll
    for (int i = 0; i < 16; ++i) {
        unsigned bin = (unsigned)(tid * 16 + i);
        if (bin > c0) g += gh0[bin];
    }
    red[tid] = g;
    __syncthreads();
    for (int o = 128; o > 0; o >>= 1) {
        if (tid < o) red[tid] += red[tid + o];
        __syncthreads();
    }
    unsigned gAbove = red[0];
    unsigned nB = sc->nB;

    // pass 1: 12-bit hist of ckey bits [8,20)
    for (int i = tid; i < 4096; i += 256) hloc[i] = 0;
    __syncthreads();
    for (unsigned j = tid; j < nB; j += 256) atomicAdd(&hloc[ckey[j] >> 8], 1u);
    __syncthreads();
    unsigned c1, r1;
    sel4096(hloc, r0, sp, sres, tid, c1, r1);

    // pass 2: 8-bit hist of ckey bits [0,8) among bits[8,20)==c1
    hloc[tid] = 0;
    __syncthreads();
    for (unsigned j = tid; j < nB; j += 256) {
        unsigned ck = ckey[j];
        if ((ck >> 8) == c1) atomicAdd(&hloc[ck & 0xFFu], 1u);
    }
    __syncthreads();
    unsigned c2, T;
    sel256(hloc, r1, sp, sres, tid, c2, T);
    unsigned tauL = (c1 << 8) | c2;

    // pass 3: gold above tauL within bucket; collect ties
    if (tid == 0) tcnt = 0;
    __syncthreads();
    unsigned gb = 0;
    for (unsigned j = tid; j < nB; j += 256) {
        unsigned ck = ckey[j];
        if (ck > tauL) gb += cidx[j] & 1u;
        else if (ck == tauL) {
            unsigned p = atomicAdd(&tcnt, 1u);
            if (p < 4096) tie[p] = cidx[j];
        }
    }
    red[tid] = gb;
    __syncthreads();
    for (int o = 128; o > 0; o >>= 1) {
        if (tid < o) red[tid] += red[tid + o];
        __syncthreads();
    }
    if (tid == 0) {
        unsigned gBnd = red[0];
        unsigned neq = tcnt; if (neq > 4096) neq = 4096;
        unsigned extra = 0;
        if (T >= neq) {
            for (unsigned i = 0; i < neq; ++i) extra += tie[i] & 1u;
        } else {
            // take T ties with lowest span index (matches lax.top_k tie order)
            unsigned prev = 0; bool first = true;
            for (unsigned it = 0; it < T; ++it) {
                unsigned mn = 0xFFFFFFFFu; unsigned mng = 0;
                for (unsigned i = 0; i < neq; ++i) {
                    unsigned v = tie[i]; unsigned idx = v >> 1;
                    if ((first || idx > prev) && idx < mn) { mn = idx; mng = v & 1u; }
                }
                if (mn == 0xFFFFFFFFu) break;
                extra += mng;
                prev = mn; first = false;
            }
        }
        out[0] = sc->loss_sum / (float)sc->n_valid;
        out[1] = (float)(gAbove + gBnd + extra) / (float)KSEL;
    }
}

extern "C" void kernel_launch(void* const* d_in, const int* in_sizes, int n_in,
                              void* d_out, int out_size, void* d_ws, size_t ws_size,
                              hipStream_t stream) {
    const float* hidden   = (const float*)d_in[0];
    const float* term_w   = (const float*)d_in[1];
    const float* w_in     = (const float*)d_in[2];
    const float* b_in     = (const float*)d_in[3];
    const float* score_w  = (const float*)d_in[4];
    const float* score_b  = (const float*)d_in[5];
    const int*   seq_len  = (const int*)d_in[6];
    const int*   gmask    = (const int*)d_in[7];
    float* out            = (float*)d_out;
    char*  ws             = (char*)d_ws;

    k_query  <<<256, 256, 0, stream>>>(w_in, term_w, b_in, ws);
    k_dots   <<<4096, 256, 0, stream>>>(hidden, score_w, ws);
    k_scores <<<64, 256, 0, stream>>>(gmask, seq_len, score_b, ws);
    k_compact<<<64, 256, 0, stream>>>(ws, gmask);
    k_final  <<<1, 256, 0, stream>>>(ws, out);
}